// Round 5
// baseline (467.917 us; speedup 1.0000x reference)
//
#include <hip/hip_runtime.h>

#define B_TOT 4096
#define S_LEN 1024
#define HID 30
#define SKIP 16
#define HLEN (S_LEN - SKIP)   // 1008
#define WARM 32               // h2 warm-up steps for chunks >= 1

// ---- DPP helpers (16-lane groups == DPP rows) ----
template <int CTRL>
__device__ __forceinline__ float dppmov(float v) {
  return __int_as_float(__builtin_amdgcn_update_dpp(
      0, __float_as_int(v), CTRL, 0xF, 0xF, true));
}
template <int CTRL>
__device__ __forceinline__ float dpp_add(float v) { return v + dppmov<CTRL>(v); }

// lane l -> value of lane l^16 (ds_swizzle BitMode, confined to 32-lane group,
// so the two batches in a wave never mix)
__device__ __forceinline__ float swz16(float v) {
  return __int_as_float(__builtin_amdgcn_ds_swizzle(__float_as_int(v), 0x401F));
}

// sum over each 16-lane group; result valid in ALL 16 lanes
__device__ __forceinline__ float red16(float v) {
  v = dpp_add<0xB1>(v);    // xor1
  v = dpp_add<0x4E>(v);    // xor2
  v = dpp_add<0x141>(v);   // xor7 (row_half_mirror)
  v = dpp_add<0x140>(v);   // xor15 (row_mirror)
  return v;
}
// sum over each 32-lane group; valid in all 32 lanes
__device__ __forceinline__ float red32(float v) {
  v = red16(v);
  v += swz16(v);
  return v;
}

// all-gather: a[m] = value of lane (lane ^ m) within the 16-group
__device__ __forceinline__ void gather16(float h, float* a) {
  a[0]  = h;
  a[1]  = dppmov<0xB1>(h);      // xor1
  a[2]  = dppmov<0x4E>(h);      // xor2
  a[3]  = dppmov<0x1B>(h);      // xor3
  a[7]  = dppmov<0x141>(h);     // xor7
  a[15] = dppmov<0x140>(h);     // xor15
  a[4]  = dppmov<0x1B>(a[7]);   // 7^3
  a[5]  = dppmov<0x4E>(a[7]);   // 7^2
  a[6]  = dppmov<0xB1>(a[7]);   // 7^1
  a[8]  = dppmov<0x141>(a[15]); // 15^7
  a[12] = dppmov<0x1B>(a[15]);  // 15^3
  a[13] = dppmov<0x4E>(a[15]);  // 15^2
  a[14] = dppmov<0xB1>(a[15]);  // 15^1
  a[9]  = dppmov<0xB1>(a[8]);   // 8^1
  a[10] = dppmov<0x4E>(a[8]);   // 8^2
  a[11] = dppmov<0x1B>(a[8]);   // 8^3
}

__device__ __forceinline__ float sigmoid_fast(float z) {
  float e = __builtin_amdgcn_exp2f(z * -1.442695041f);   // exp(-z)
  return __builtin_amdgcn_rcpf(1.0f + e);                // 1/(1+e)
}

// Time-chunked RNN scan, ALL-F32 math (Round-4 lesson: the trapezoid
// integral P has heavy cancellation, so f16-quantized Wh shifts H
// coherently and blows the Output-1 (log10 P) tolerance; Wh.h must be f32).
//
// Round-5 restructure: ONE Wh row per lane, 32 lanes per batch (was 2 rows
// x 16 lanes). Halves the per-lane weight array (64->32 f32) and the inner
// FMA count (64->32); cross-lane gather = 2x DPP-gather16 + one ds_swizzle
// xor16. Live set ~115 VGPR -> no AGPR shuffling (Round-2's hidden cost),
// ~4 waves/SIMD resident of an 8-wave/SIMD workload.
//
// Block = 256 thr = 4 waves = 2 batches x 4 chunk-waves.
// Chunk boundaries {16,280,528,776,1024}: every chunk runs exactly 280 full
// RNN steps (chunks>=1: 32 warm-up + 248 outputs). h2 recurrence is
// contracting (||diag(sig')Wh|| <~ 0.35/step) so 32 warm-up steps leave
// <1e-14 state error (validated: R2 passed with baseline absmax). s1 is NOT
// contracting -> each chunk rescans s1 exactly from t=0 (~3 instr/step).
__global__ __launch_bounds__(256) void mminet_fused(
    const float* __restrict__ x,   const float* __restrict__ var,
    const float* __restrict__ amps,const float* __restrict__ s0,
    const float* __restrict__ W1,  const float* __restrict__ b1,
    const float* __restrict__ Wx,  const float* __restrict__ Wh,
    const float* __restrict__ W2,  const float* __restrict__ b2,
    const float* __restrict__ Wm1, const float* __restrict__ bm1,
    const float* __restrict__ Wm2, const float* __restrict__ bm2,
    const float* __restrict__ Wm3, const float* __restrict__ bm3,
    float* __restrict__ Hout, float* __restrict__ out2)
{
  __shared__ float mlpbuf[2][64];            // epilogue, wave 0 only
  __shared__ float Pred[4][2];               // [chunk][batch_local]
  const int tid   = threadIdx.x;
  const int l     = tid & 31;                // lane within 32-group
  const int g     = tid >> 5;                // group within block (0..7)
  const int chunk = g >> 1;                  // == wave id (wave-uniform)
  const int bl    = g & 1;                   // batch within block
  const int b     = blockIdx.x * 2 + bl;
  const int j     = l;                       // Wh row (30,31 dummy)
  const bool ar   = (j < HID);

  // chunk output ranges: balanced so each wave does 280 full steps
  const int ob = (chunk == 0) ? SKIP : (chunk == 1) ? 280 : (chunk == 2) ? 528 : 776;
  const int oe = (chunk == 0) ? 280  : (chunk == 1) ? 528 : (chunk == 2) ? 776 : 1024;

  const float v0 = var[b*4+0], v1 = var[b*4+1], v2 = var[b*4+2], v3 = var[b*4+3];

  // ---- per-lane row constants ----
  float wx0=0,wx1=0,wx2=0,cv=0,w1=0,w2=0;
  if (ar) {
    wx0 = Wx[j*7+0]; wx1 = Wx[j*7+1]; wx2 = Wx[j*7+2];
    cv  = Wx[j*7+3]*v0 + Wx[j*7+4]*v1 + Wx[j*7+5]*v2 + Wx[j*7+6]*v3;
    w1  = W1[j]; w2 = W2[j];
  }

  // ---- Wh row j in xor-relative order: wh[m] = Wh[j][l^m], m=0..31 ----
  // he[m] (m<16) is h of lane l^m; hf[k] is h of lane l^16^k = l^(16+k),
  // so wh[m] pairs he[m] and wh[16+k] pairs hf[k] -- one flat indexing.
  float wh[32];
  float rowsum = 0.f;
#pragma unroll
  for (int m = 0; m < 32; ++m) {
    const int c = l ^ m;
    float wv = (ar && c < HID) ? Wh[j*HID + c] : 0.f;
    wh[m] = wv;
    rowsum += wv;
  }

  const float hcst = W1[30]*v0 + W1[31]*v1 + W1[32]*v2 + W1[33]*v3 + b1[0];
  const float hc2  = hcst + b2[0];
  const float sumW2 = red32(w2);

  const float r = 5.0f * (float)(j + 1) / 30.0f;

  const float4* xb = (const float4*)(x + (size_t)b * S_LEN * 4);

  // ---- state ----
  float s1 = ar ? s0[b*HID + j] : 0.f;
  float h  = 0.5f;

  // one RNN step: 4 independent f32 FMA chains of 8
  auto step = [&](const float4 xq) -> float {
    s1 = fminf(fmaxf(xq.y + s1, -r), r);
    float hsw = swz16(h);                 // issue LDS-pipe op early
    float he[16];
    gather16(h, he);                      // DPP while swizzle in flight
    float z0 = fmaf(wx0, xq.x, cv);
    float z1 = fmaf(wx1, xq.z, wx2 * xq.w);
    float z2 = 0.f, z3 = 0.f;
#pragma unroll
    for (int m = 0; m < 8; ++m) {
      z0 = fmaf(wh[m],    he[m],   z0);
      z1 = fmaf(wh[m+8],  he[m+8], z1);
    }
    float hf[16];
    gather16(hsw, hf);
#pragma unroll
    for (int m = 0; m < 8; ++m) {
      z2 = fmaf(wh[m+16], hf[m],   z2);
      z3 = fmaf(wh[m+24], hf[m+8], z3);
    }
    h = sigmoid_fast((z0 + z2) + (z1 + z3));
    return fmaf(w1, s1, w2 * h);
  };

  float P = 0.f, Hprev = 0.f, Bprev = 0.f;

  if (chunk == 0) {
    // ---- t = 0 prologue (exact reference init) ----
    float4 xv = xb[0];
    s1 = fminf(fmaxf(xv.y + s1, -r), r);
    float Hh0 = red32(w1 * s1) + hcst;
    float hpre = (xv.x - Hh0) / sumW2;       // uniform initial h2
    float z = cv + wx0*xv.x + wx1*xv.z + wx2*xv.w + rowsum*hpre;
    h = sigmoid_fast(z);
    // ---- t = 1..15 : outputs discarded, recurrence only ----
    for (int t = 1; t < SKIP; ++t) (void)step(xb[t]);
  } else {
    // ---- s1-only exact prescan over [0, ob-WARM) ----
    const int ps = ob - WARM;                // 248 / 496 / 744, all %8==0
    for (int t = 0; t < ps; t += 8) {
      float d[8];
#pragma unroll
      for (int u = 0; u < 8; ++u) d[u] = xb[t + u].y;
#pragma unroll
      for (int u = 0; u < 8; ++u)
        s1 = fminf(fmaxf(d[u] + s1, -r), r);
    }
    // ---- h2 warm-up over [ps, ob): 32 full steps from h=0.5 ----
    float plast = 0.f, Blast = 0.f;
    float4 q0 = xb[ps+0], q1 = xb[ps+1], q2 = xb[ps+2], q3 = xb[ps+3];
    for (int t = ps; t < ob; t += 4) {
      const int tn = (t + 4 < ob) ? (t + 4) : t;
      float4 n0 = xb[tn+0], n1 = xb[tn+1], n2 = xb[tn+2], n3 = xb[tn+3];
      (void)step(q0); (void)step(q1); (void)step(q2);
      plast = step(q3); Blast = q3.x;
      q0 = n0; q1 = n1; q2 = n2; q3 = n3;
    }
    Hprev = red32(plast) + hc2;              // H at t = ob-1 (boundary pair)
    Bprev = Blast;
  }

  // ---- output steps t = ob..oe-1 in blocks of 4 ----
  float4 xc0 = xb[ob+0], xc1 = xb[ob+1], xc2 = xb[ob+2], xc3 = xb[ob+3];

  for (int t = ob; t < oe; t += 4) {
    const int tn = (t + 4 < oe) ? (t + 4) : t;   // uniform
    float4 xn0 = xb[tn+0], xn1 = xb[tn+1], xn2 = xb[tn+2], xn3 = xb[tn+3];

    float p[4], x0s[4];
    x0s[0] = xc0.x;  p[0] = step(xc0);
    x0s[1] = xc1.x;  p[1] = step(xc1);
    x0s[2] = xc2.x;  p[2] = step(xc2);
    x0s[3] = xc3.x;  p[3] = step(xc3);

#pragma unroll
    for (int u = 0; u < 4; ++u) p[u] = red32(p[u]);

    float hq[4];
#pragma unroll
    for (int u = 0; u < 4; ++u) {
      float Ht = p[u] + hc2;
      hq[u] = Ht;
      if (t + u > SKIP) P += (x0s[u] - Bprev) * (Ht + Hprev);
      Hprev = Ht; Bprev = x0s[u];
    }
    if (l == 0) {
      *(float4*)(Hout + (size_t)b * HLEN + (t - SKIP)) =
          make_float4(hq[0], hq[1], hq[2], hq[3]);
    }
    xc0 = xn0; xc1 = xn1; xc2 = xn2; xc3 = xn3;
  }

  // ---- cross-chunk trapezoid-sum reduction ----
  if (l == 0) Pred[chunk][bl] = P;
  __syncthreads();
  if (chunk != 0) return;

  const float Ptot = Pred[0][bl] + Pred[1][bl] + Pred[2][bl] + Pred[3][bl];

  // ==== fused MLP epilogue (wave 0; each 32-half owns its batch) ====
  const float am0 = amps[b*2+0], am1 = amps[b*2+1];
  float Pp = Ptot * 0.5f * am0 * am1;
  Pp *= __builtin_amdgcn_exp2f(v0 * 3.321928095f);     // * 10^var0
  Pp = fmaxf(Pp, 1e-12f);
  const float Pcv = __builtin_amdgcn_logf(Pp) * 0.30102999566f;  // log10

  float* hs = &mlpbuf[bl][0];
#pragma unroll
  for (int q = 0; q < 2; ++q) {
    const int n = l + 32 * q;
    const float* wr = Wm1 + n * 5;
    float h1 = bm1[n] + wr[0]*v0 + wr[1]*v1 + wr[2]*v2 + wr[3]*v3 + wr[4]*Pcv;
    hs[n] = fmaxf(h1, 0.f);                  // wave-synchronous within wave 0
  }
  // layer 2: row m = l (exactly 32 rows)
  const float4* h1v = (const float4*)hs;
  const float4* w2r = (const float4*)(Wm2 + l * 64);
  float z = bm2[l];
#pragma unroll
  for (int q = 0; q < 16; ++q) {
    float4 hh = h1v[q];
    float4 wa = w2r[q];
    z += wa.x*hh.x + wa.y*hh.y + wa.z*hh.z + wa.w*hh.w;
  }
  float sp = Wm3[l] * fmaxf(z, 0.f);
  sp = red32(sp);
  if (l == 0) out2[b] = Pcv + sp + bm3[0];
}

extern "C" void kernel_launch(void* const* d_in, const int* in_sizes, int n_in,
                              void* d_out, int out_size, void* d_ws, size_t ws_size,
                              hipStream_t stream)
{
  const float* x    = (const float*)d_in[0];
  const float* var  = (const float*)d_in[1];
  const float* amps = (const float*)d_in[2];
  const float* s0   = (const float*)d_in[3];
  const float* W1   = (const float*)d_in[4];
  const float* b1   = (const float*)d_in[5];
  const float* Wx   = (const float*)d_in[6];
  const float* Wh   = (const float*)d_in[7];
  const float* W2   = (const float*)d_in[8];
  const float* b2   = (const float*)d_in[9];
  const float* Wm1  = (const float*)d_in[10];
  const float* bm1  = (const float*)d_in[11];
  const float* Wm2  = (const float*)d_in[12];
  const float* bm2  = (const float*)d_in[13];
  const float* Wm3  = (const float*)d_in[14];
  const float* bm3  = (const float*)d_in[15];
  // d_in[16] = n_init (compile-time 16)

  float* Hout = (float*)d_out;
  float* out2 = (float*)d_out + (size_t)B_TOT * HLEN;

  mminet_fused<<<B_TOT / 2, 256, 0, stream>>>(
      x, var, amps, s0, W1, b1, Wx, Wh, W2, b2,
      Wm1, bm1, Wm2, bm2, Wm3, bm3, Hout, out2);
}

// Round 6
// 395.128 us; speedup vs baseline: 1.1842x; 1.1842x over previous
//
#include <hip/hip_runtime.h>

#define B_TOT 4096
#define S_LEN 1024
#define HID 30
#define SKIP 16
#define HLEN (S_LEN - SKIP)   // 1008
#define WARM 32               // h2 warm-up steps for chunks >= 1

typedef float v2f __attribute__((ext_vector_type(2)));

// ---- DPP helpers (16-lane groups == DPP rows) ----
template <int CTRL>
__device__ __forceinline__ float dppmov(float v) {
  return __int_as_float(__builtin_amdgcn_update_dpp(
      0, __float_as_int(v), CTRL, 0xF, 0xF, true));
}
template <int CTRL>
__device__ __forceinline__ float dpp_add(float v) { return v + dppmov<CTRL>(v); }

// sum over each 16-lane group; result valid in ALL 16 lanes
__device__ __forceinline__ float red16(float v) {
  v = dpp_add<0xB1>(v);    // quad_perm [1,0,3,2] : xor1
  v = dpp_add<0x4E>(v);    // quad_perm [2,3,0,1] : xor2
  v = dpp_add<0x141>(v);   // row_half_mirror     : xor7
  v = dpp_add<0x140>(v);   // row_mirror          : xor15
  return v;
}

// all-gather: a[m] = value of lane (lane ^ m) within the 16-group
__device__ __forceinline__ void gather16(float h, float* a) {
  a[0]  = h;
  a[1]  = dppmov<0xB1>(h);      // xor1
  a[2]  = dppmov<0x4E>(h);      // xor2
  a[3]  = dppmov<0x1B>(h);      // xor3
  a[7]  = dppmov<0x141>(h);     // xor7
  a[15] = dppmov<0x140>(h);     // xor15
  a[4]  = dppmov<0x1B>(a[7]);   // 7^3
  a[5]  = dppmov<0x4E>(a[7]);   // 7^2
  a[6]  = dppmov<0xB1>(a[7]);   // 7^1
  a[8]  = dppmov<0x141>(a[15]); // 15^7
  a[12] = dppmov<0x1B>(a[15]);  // 15^3
  a[13] = dppmov<0x4E>(a[15]);  // 15^2
  a[14] = dppmov<0xB1>(a[15]);  // 15^1
  a[9]  = dppmov<0xB1>(a[8]);   // 8^1
  a[10] = dppmov<0x4E>(a[8]);   // 8^2
  a[11] = dppmov<0x1B>(a[8]);   // 8^3
}

__device__ __forceinline__ float sigmoid_fast(float z) {
  float e = __builtin_amdgcn_exp2f(z * -1.442695041f);   // exp(-z)
  return __builtin_amdgcn_rcpf(1.0f + e);                // 1/(1+e)
}

__device__ __forceinline__ v2f bc2(float v) { return (v2f){v, v}; }

// med3 clamp: s in [-r, r], one v_med3_f32 per component
__device__ __forceinline__ v2f clamp2(v2f s, v2f r) {
  s.x = __builtin_amdgcn_fmed3f(s.x, -r.x, r.x);
  s.y = __builtin_amdgcn_fmed3f(s.y, -r.y, r.y);
  return s;
}

// Time-chunked RNN scan, ALL-F32 math.
// Lesson ledger: (R1) never cap VGPR below live set; (R4) Wh.h must stay
// f32 -- the trapezoid-integral output amplifies coherent H bias ~10x;
// (R5) time ~ TOTAL wave-instructions x ~4.8cyc/SIMD regardless of
// occupancy; the 30-DPP h-gather is a fixed floor per wave-step, so
// 4 batches/wave (16 lanes, 2 rows/lane) minimizes instr/batch-step.
//
// Round-6: halve the FMA count with packed-f32 VALU (v_pk_fma_f32,
// full-rate on CDNA, bit-exact f32): rows (j0,j1) packed as float2,
// 64 fma -> 32 pk_fma; med3 clamps; packed z-init/H-partial.
//
// Block = 256 thr = 4 batches x 4 chunk-waves.
// Chunk boundaries {16,280,528,776,1024}: every chunk runs exactly 280 full
// RNN steps (chunks>=1: 32 warm-up + 248 outputs). h2 recurrence is
// contracting (||diag(sig')Wh|| <~ 0.35/step) so 32 warm-up steps leave
// <1e-14 state error (validated R2/R5). s1 is NOT contracting -> each
// chunk rescans s1 exactly from t=0 (3 instr/step with med3).
__global__ __launch_bounds__(256) void mminet_fused(
    const float* __restrict__ x,   const float* __restrict__ var,
    const float* __restrict__ amps,const float* __restrict__ s0,
    const float* __restrict__ W1,  const float* __restrict__ b1,
    const float* __restrict__ Wx,  const float* __restrict__ Wh,
    const float* __restrict__ W2,  const float* __restrict__ b2,
    const float* __restrict__ Wm1, const float* __restrict__ bm1,
    const float* __restrict__ Wm2, const float* __restrict__ bm2,
    const float* __restrict__ Wm3, const float* __restrict__ bm3,
    float* __restrict__ Hout, float* __restrict__ out2)
{
  __shared__ float mlpbuf[4][64];            // epilogue, wave 0 only
  __shared__ float Pred[4][4];               // [chunk][batch_local]
  const int tid   = threadIdx.x;
  const int l     = tid & 15;                // lane within 16-group
  const int grp   = tid >> 4;                // group within block (0..15)
  const int chunk = grp >> 2;                // == wave id (wave-uniform)
  const int bl    = grp & 3;                 // batch within block
  const int b     = blockIdx.x * 4 + bl;
  const int j0    = 2 * l, j1 = 2 * l + 1;
  const bool a0r  = (j0 < HID), a1r = (j1 < HID);

  // chunk output ranges: balanced so each wave does 280 full steps
  const int ob = (chunk == 0) ? SKIP : (chunk == 1) ? 280 : (chunk == 2) ? 528 : 776;
  const int oe = (chunk == 0) ? 280  : (chunk == 1) ? 528 : (chunk == 2) ? 776 : 1024;

  const float v0 = var[b*4+0], v1 = var[b*4+1], v2 = var[b*4+2], v3 = var[b*4+3];

  // ---- per-lane row constants, packed (row j0, row j1) ----
  v2f wxp0 = {0,0}, wxp1 = {0,0}, wxp2 = {0,0}, cvp = {0,0};
  v2f w1p = {0,0}, w2p = {0,0};
  if (a0r) {
    wxp0.x = Wx[j0*7+0]; wxp1.x = Wx[j0*7+1]; wxp2.x = Wx[j0*7+2];
    cvp.x  = Wx[j0*7+3]*v0 + Wx[j0*7+4]*v1 + Wx[j0*7+5]*v2 + Wx[j0*7+6]*v3;
    w1p.x  = W1[j0]; w2p.x = W2[j0];
  }
  if (a1r) {
    wxp0.y = Wx[j1*7+0]; wxp1.y = Wx[j1*7+1]; wxp2.y = Wx[j1*7+2];
    cvp.y  = Wx[j1*7+3]*v0 + Wx[j1*7+4]*v1 + Wx[j1*7+5]*v2 + Wx[j1*7+6]*v3;
    w1p.y  = W1[j1]; w2p.y = W2[j1];
  }

  // ---- Wh in xor-relative order, packed across the two rows ----
  // wp0[m] = (Wh[j0][2lp], Wh[j1][2lp])  -> multiplies he[m] = hA of lane lp
  // wp1[m] = (Wh[j0][2lp+1], Wh[j1][2lp+1]) -> multiplies ho[m] = hB of lp
  v2f wp0[16], wp1[16];
  v2f rowsp = {0,0};
#pragma unroll
  for (int m = 0; m < 16; ++m) {
    const int lp = l ^ m;
    const int c0 = 2 * lp, c1 = 2 * lp + 1;
    float a0 = (a0r && c0 < HID) ? Wh[j0*HID + c0] : 0.f;
    float a1 = (a0r && c1 < HID) ? Wh[j0*HID + c1] : 0.f;
    float b0 = (a1r && c0 < HID) ? Wh[j1*HID + c0] : 0.f;
    float b1w= (a1r && c1 < HID) ? Wh[j1*HID + c1] : 0.f;
    wp0[m] = (v2f){a0, b0};
    wp1[m] = (v2f){a1, b1w};
    rowsp += wp0[m] + wp1[m];
  }

  const float hcst = W1[30]*v0 + W1[31]*v1 + W1[32]*v2 + W1[33]*v3 + b1[0];
  const float hc2  = hcst + b2[0];
  const float sumW2 = red16(w2p.x + w2p.y);

  const v2f rp = {5.0f * (float)(j0 + 1) / 30.0f,
                  5.0f * (float)(j1 + 1) / 30.0f};

  const float4* xb = (const float4*)(x + (size_t)b * S_LEN * 4);

  // ---- state ----
  v2f s1p = { a0r ? s0[b*HID + j0] : 0.f,
              a1r ? s0[b*HID + j1] : 0.f };
  float hA = 0.5f, hB = 0.5f;

  // one RNN step: 4 independent pk_fma chains of 8
  auto step = [&](const float4 xq) -> float {
    s1p = clamp2(s1p + bc2(xq.y), rp);
    float he[16], ho[16];
    gather16(hA, he);
    gather16(hB, ho);
    v2f z0 = wxp0 * bc2(xq.x) + cvp;          // pk_fma
    v2f z1 = wxp1 * bc2(xq.z) + wxp2 * bc2(xq.w);
    v2f z2 = {0,0}, z3 = {0,0};
#pragma unroll
    for (int m = 0; m < 8; ++m) {
      z0 = wp0[m]   * bc2(he[m])   + z0;
      z1 = wp1[m]   * bc2(ho[m])   + z1;
      z2 = wp0[m+8] * bc2(he[m+8]) + z2;
      z3 = wp1[m+8] * bc2(ho[m+8]) + z3;
    }
    v2f z = (z0 + z2) + (z1 + z3);
    hA = sigmoid_fast(z.x);
    hB = sigmoid_fast(z.y);
    v2f acc = w1p * s1p + w2p * (v2f){hA, hB};
    return acc.x + acc.y;
  };

  float P = 0.f, Hprev = 0.f, Bprev = 0.f;

  if (chunk == 0) {
    // ---- t = 0 prologue (exact reference init) ----
    float4 xv = xb[0];
    s1p = clamp2(s1p + bc2(xv.y), rp);
    v2f t1 = w1p * s1p;
    float Hh0 = red16(t1.x + t1.y) + hcst;
    float hpre = (xv.x - Hh0) / sumW2;         // uniform initial h2
    v2f z = cvp + wxp0*bc2(xv.x) + wxp1*bc2(xv.z) + wxp2*bc2(xv.w)
                + rowsp*bc2(hpre);
    hA = sigmoid_fast(z.x);
    hB = sigmoid_fast(z.y);
    // ---- t = 1..15 : outputs discarded, recurrence only ----
    for (int t = 1; t < SKIP; ++t) (void)step(xb[t]);
  } else {
    // ---- s1-only exact prescan over [0, ob-WARM) ----
    const int ps = ob - WARM;                  // 248 / 496 / 744, all %8==0
    for (int t = 0; t < ps; t += 8) {
      float d[8];
#pragma unroll
      for (int u = 0; u < 8; ++u) d[u] = xb[t + u].y;
#pragma unroll
      for (int u = 0; u < 8; ++u)
        s1p = clamp2(s1p + bc2(d[u]), rp);
    }
    // ---- h2 warm-up over [ps, ob): 32 full steps from h=0.5 ----
    float plast = 0.f, Blast = 0.f;
    float4 q0 = xb[ps+0], q1 = xb[ps+1], q2 = xb[ps+2], q3 = xb[ps+3];
    for (int t = ps; t < ob; t += 4) {
      const int tn = (t + 4 < ob) ? (t + 4) : t;
      float4 n0 = xb[tn+0], n1 = xb[tn+1], n2 = xb[tn+2], n3 = xb[tn+3];
      (void)step(q0); (void)step(q1); (void)step(q2);
      plast = step(q3); Blast = q3.x;
      q0 = n0; q1 = n1; q2 = n2; q3 = n3;
    }
    Hprev = red16(plast) + hc2;                // H at t = ob-1 (boundary pair)
    Bprev = Blast;
  }

  // ---- output steps t = ob..oe-1 in blocks of 4 ----
  const float am0 = amps[b*2+0], am1 = amps[b*2+1];

  float4 xc0 = xb[ob+0], xc1 = xb[ob+1], xc2 = xb[ob+2], xc3 = xb[ob+3];

  for (int t = ob; t < oe; t += 4) {
    const int tn = (t + 4 < oe) ? (t + 4) : t;   // uniform
    float4 xn0 = xb[tn+0], xn1 = xb[tn+1], xn2 = xb[tn+2], xn3 = xb[tn+3];

    float p[4], x0s[4];
    x0s[0] = xc0.x;  p[0] = step(xc0);
    x0s[1] = xc1.x;  p[1] = step(xc1);
    x0s[2] = xc2.x;  p[2] = step(xc2);
    x0s[3] = xc3.x;  p[3] = step(xc3);

#pragma unroll
    for (int u = 0; u < 4; ++u) p[u] = red16(p[u]);

    float hq[4];
#pragma unroll
    for (int u = 0; u < 4; ++u) {
      float Ht = p[u] + hc2;
      hq[u] = Ht;
      if (t + u > SKIP) P += (x0s[u] - Bprev) * (Ht + Hprev);
      Hprev = Ht; Bprev = x0s[u];
    }
    if (l == 0) {
      *(float4*)(Hout + (size_t)b * HLEN + (t - SKIP)) =
          make_float4(hq[0], hq[1], hq[2], hq[3]);
    }
    xc0 = xn0; xc1 = xn1; xc2 = xn2; xc3 = xn3;
  }

  // ---- cross-chunk trapezoid-sum reduction ----
  if (l == 0) Pred[chunk][bl] = P;
  __syncthreads();
  if (chunk != 0) return;

  const float Ptot = Pred[0][bl] + Pred[1][bl] + Pred[2][bl] + Pred[3][bl];

  // ==== fused MLP epilogue (wave 0; P valid in all 16 lanes) ====
  float Pp = Ptot * 0.5f * am0 * am1;
  Pp *= __builtin_amdgcn_exp2f(v0 * 3.321928095f);     // * 10^var0
  Pp = fmaxf(Pp, 1e-12f);
  const float Pcv = __builtin_amdgcn_logf(Pp) * 0.30102999566f;  // log10

  float* hs = &mlpbuf[grp][0];
#pragma unroll
  for (int q = 0; q < 4; ++q) {
    const int n = l + 16 * q;
    const float* wr = Wm1 + n * 5;
    float h1 = bm1[n] + wr[0]*v0 + wr[1]*v1 + wr[2]*v2 + wr[3]*v3 + wr[4]*Pcv;
    hs[n] = fmaxf(h1, 0.f);                  // wave-synchronous within wave 0
  }
  const int m0 = l, m1 = l + 16;
  const float4* h1v = (const float4*)hs;
  const float4* w2a = (const float4*)(Wm2 + m0 * 64);
  const float4* w2b = (const float4*)(Wm2 + m1 * 64);
  float z0 = bm2[m0], z1 = bm2[m1];
#pragma unroll
  for (int q = 0; q < 16; ++q) {
    float4 hh = h1v[q];
    float4 wa = w2a[q], wb = w2b[q];
    z0 += wa.x*hh.x + wa.y*hh.y + wa.z*hh.z + wa.w*hh.w;
    z1 += wb.x*hh.x + wb.y*hh.y + wb.z*hh.z + wb.w*hh.w;
  }
  float sp = Wm3[m0] * fmaxf(z0, 0.f) + Wm3[m1] * fmaxf(z1, 0.f);
  sp = red16(sp);
  if (l == 0) out2[b] = Pcv + sp + bm3[0];
}

extern "C" void kernel_launch(void* const* d_in, const int* in_sizes, int n_in,
                              void* d_out, int out_size, void* d_ws, size_t ws_size,
                              hipStream_t stream)
{
  const float* x    = (const float*)d_in[0];
  const float* var  = (const float*)d_in[1];
  const float* amps = (const float*)d_in[2];
  const float* s0   = (const float*)d_in[3];
  const float* W1   = (const float*)d_in[4];
  const float* b1   = (const float*)d_in[5];
  const float* Wx   = (const float*)d_in[6];
  const float* Wh   = (const float*)d_in[7];
  const float* W2   = (const float*)d_in[8];
  const float* b2   = (const float*)d_in[9];
  const float* Wm1  = (const float*)d_in[10];
  const float* bm1  = (const float*)d_in[11];
  const float* Wm2  = (const float*)d_in[12];
  const float* bm2  = (const float*)d_in[13];
  const float* Wm3  = (const float*)d_in[14];
  const float* bm3  = (const float*)d_in[15];
  // d_in[16] = n_init (compile-time 16)

  float* Hout = (float*)d_out;
  float* out2 = (float*)d_out + (size_t)B_TOT * HLEN;

  mminet_fused<<<B_TOT / 4, 256, 0, stream>>>(
      x, var, amps, s0, W1, b1, Wx, Wh, W2, b2,
      Wm1, bm1, Wm2, bm2, Wm3, bm3, Hout, out2);
}

// Round 7
// 290.220 us; speedup vs baseline: 1.6123x; 1.3615x over previous
//
#include <hip/hip_runtime.h>

#define B_TOT 4096
#define S_LEN 1024
#define HID 30
#define SKIP 16
#define HLEN (S_LEN - SKIP)   // 1008
#define WARM 32               // h2 warm-up steps for chunks >= 1

typedef float f32x4 __attribute__((ext_vector_type(4)));
typedef short bf16x8 __attribute__((ext_vector_type(8)));
typedef int   i32x4  __attribute__((ext_vector_type(4)));

// ---- DPP helpers (epilogue red16 only) ----
template <int CTRL>
__device__ __forceinline__ float dppmov(float v) {
  return __int_as_float(__builtin_amdgcn_update_dpp(
      0, __float_as_int(v), CTRL, 0xF, 0xF, true));
}
template <int CTRL>
__device__ __forceinline__ float dpp_add(float v) { return v + dppmov<CTRL>(v); }
__device__ __forceinline__ float red16(float v) {
  v = dpp_add<0xB1>(v); v = dpp_add<0x4E>(v);
  v = dpp_add<0x141>(v); v = dpp_add<0x140>(v);
  return v;
}
// lane l <- lane l^16 (ds_swizzle BitMode xor16, within 32-lane half)
__device__ __forceinline__ float swz16(float v) {
  return __int_as_float(__builtin_amdgcn_ds_swizzle(__float_as_int(v), 0x401F));
}
__device__ __forceinline__ float sigmoid_fast(float z) {
  float e = __builtin_amdgcn_exp2f(z * -1.442695041f);
  return __builtin_amdgcn_rcpf(1.0f + e);
}
// v_cvt_pk_bf16_f32: two f32 -> one u32 of two bf16 (no builtin on gfx950)
__device__ __forceinline__ int cvt_pk_bf16(float a, float b) {
  int r; asm("v_cvt_pk_bf16_f32 %0, %1, %2" : "=v"(r) : "v"(a), "v"(b)); return r;
}
// split 8 f32 into hi/lo bf16 words (hi = bf16(v), lo = bf16(v - f32(hi)))
__device__ __forceinline__ void split8(const float* v, int* hw, int* lw) {
#pragma unroll
  for (int p = 0; p < 4; ++p) {
    int h = cvt_pk_bf16(v[2*p], v[2*p+1]);
    float f0 = __int_as_float(h << 16);
    float f1 = __int_as_float(h & 0xffff0000);
    lw[p] = cvt_pk_bf16(v[2*p] - f0, v[2*p+1] - f1);
    hw[p] = h;
  }
}
__device__ __forceinline__ bf16x8 frag4(const int* w) {
  return __builtin_bit_cast(bf16x8, (i32x4){w[0], w[1], w[2], w[3]});
}

// Time-chunked RNN scan with MFMA inner product.
// Lesson ledger: (R1) VGPR cap >= live set; (R4) plain f16/bf16 Wh.h is
// fatal (trapezoid-integral output amplifies coherent H bias) -> use
// split-bf16 3-product MFMA (z-err ~3e-6, 100x margin vs R4's failure);
// (R5/R6) time ~ total wave-instrs x ~4.8cyc regardless of occupancy ->
// the lever is instrs/batch-step: MFMA serves 16 batches/wave-step.
//
// Wave layout: batch = lane&15 (16 batches/wave), q = lane>>4.
// Slot->unit map (shared by A and B, so any HW k-permutation cancels):
//   slot kk<4 -> unit 4q+kk ; kk>=4 -> unit 16+4q+(kk-4)
// D-layout (m89-verified): col=lane&15(batch), row=4q+reg (acc0) /
// 16+4q+reg (acc1) == the same unit set -> sigmoid output feeds next
// step's B-operand entirely IN-LANE (no cross-lane gather at all).
// A-zeros at units>=30 kill the two dummy rows.
//
// Block = 256 thr = 4 chunk-waves x (same 16 batches). Chunks
// {16,280,528,776,1024}: 280 full steps each; chunks>=1: exact s1-only
// prescan from t=0 + 32-step h2 warm-up (contraction ~0.35/step, state
// err <1e-14; validated R2/R5/R6).
__global__ __launch_bounds__(256) void mminet_fused(
    const float* __restrict__ x,   const float* __restrict__ var,
    const float* __restrict__ amps,const float* __restrict__ s0,
    const float* __restrict__ W1,  const float* __restrict__ b1,
    const float* __restrict__ Wx,  const float* __restrict__ Wh,
    const float* __restrict__ W2,  const float* __restrict__ b2,
    const float* __restrict__ Wm1, const float* __restrict__ bm1,
    const float* __restrict__ Wm2, const float* __restrict__ bm2,
    const float* __restrict__ Wm3, const float* __restrict__ bm3,
    float* __restrict__ Hout, float* __restrict__ out2)
{
  __shared__ float Pred[4][16];
  __shared__ float mlpbuf[16][64];

  const int tid   = threadIdx.x;
  const int l     = tid & 63;
  const int chunk = tid >> 6;                // wave id == chunk
  const int q     = l >> 4;                  // k-block / row-subblock
  const int c     = l & 15;                  // batch column
  const int b     = blockIdx.x * 16 + c;

  const int ob = (chunk == 0) ? SKIP : (chunk == 1) ? 280 : (chunk == 2) ? 528 : 776;
  const int oe = (chunk == 0) ? 280  : (chunk == 1) ? 528 : (chunk == 2) ? 776 : 1024;

  const float v0 = var[b*4+0], v1 = var[b*4+1], v2 = var[b*4+2], v3 = var[b*4+3];

  // ---- per-lane row constants for owned D-rows (== units) ----
  float wx0[8], wx1[8], wx2[8], cva[8], w1a[8], w2a[8], rc[8], s1[8];
#pragma unroll
  for (int i = 0; i < 8; ++i) {
    const int row = (i < 4) ? (4*q + i) : (16 + 4*q + (i - 4));
    if (row < HID) {
      wx0[i] = Wx[row*7+0]; wx1[i] = Wx[row*7+1]; wx2[i] = Wx[row*7+2];
      cva[i] = Wx[row*7+3]*v0 + Wx[row*7+4]*v1 + Wx[row*7+5]*v2 + Wx[row*7+6]*v3;
      w1a[i] = W1[row]; w2a[i] = W2[row];
      rc[i]  = 5.0f * (float)(row + 1) / 30.0f;
      s1[i]  = s0[b*HID + row];
    } else {
      wx0[i]=wx1[i]=wx2[i]=cva[i]=w1a[i]=w2a[i]=s1[i]=0.f; rc[i]=1.0f;
    }
  }

  // ---- A fragments (Wh, split-bf16), rows c and 16+c ----
  float a1v[8], a2v[8];
#pragma unroll
  for (int kk = 0; kk < 8; ++kk) {
    const int u = (kk < 4) ? (4*q + kk) : (16 + 4*q + (kk - 4));
    a1v[kk] = (u < HID) ? Wh[c*HID + u] : 0.f;
    a2v[kk] = (u < HID && (16 + c) < HID) ? Wh[(16+c)*HID + u] : 0.f;
  }
  int t0[4], t1[4], t2[4], t3[4];
  split8(a1v, t0, t1); split8(a2v, t2, t3);
  const bf16x8 A1h = frag4(t0), A1l = frag4(t1);
  const bf16x8 A2h = frag4(t2), A2l = frag4(t3);

  const float hcst = W1[30]*v0 + W1[31]*v1 + W1[32]*v2 + W1[33]*v3 + b1[0];
  const float hc2  = hcst + b2[0];
  const int bpx32  = ((l ^ 32) << 2);

  // reduce over the 4 q-lanes of a batch column (xor16 + xor32)
  auto redq = [&](float v) -> float {
    v += swz16(v);
    v += __int_as_float(__builtin_amdgcn_ds_bpermute(bpx32, __float_as_int(v)));
    return v;
  };
  float sw = 0.f;
#pragma unroll
  for (int i = 0; i < 8; ++i) sw += w2a[i];
  const float sumW2 = redq(sw);

  const float4* xb = (const float4*)(x + (size_t)b * S_LEN * 4);

  bf16x8 Bhi, Blo;
  auto packB = [&](const float* hv) {
    int bh[4], bl[4];
    split8(hv, bh, bl);
    Bhi = frag4(bh); Blo = frag4(bl);
  };

  // one RNN step for 16 batches: 6 MFMA + VALU epilogue
  auto dostep = [&](const float4 xq) -> float {
#pragma unroll
    for (int i = 0; i < 8; ++i)
      s1[i] = __builtin_amdgcn_fmed3f(s1[i] + xq.y, -rc[i], rc[i]);
    f32x4 z0, z1;
#pragma unroll
    for (int i = 0; i < 4; ++i) {
      z0[i] = cva[i]   + wx0[i]*xq.x   + wx1[i]*xq.z   + wx2[i]*xq.w;
      z1[i] = cva[i+4] + wx0[i+4]*xq.x + wx1[i+4]*xq.z + wx2[i+4]*xq.w;
    }
    z0 = __builtin_amdgcn_mfma_f32_16x16x32_bf16(A1h, Bhi, z0, 0, 0, 0);
    z0 = __builtin_amdgcn_mfma_f32_16x16x32_bf16(A1l, Bhi, z0, 0, 0, 0);
    z0 = __builtin_amdgcn_mfma_f32_16x16x32_bf16(A1h, Blo, z0, 0, 0, 0);
    z1 = __builtin_amdgcn_mfma_f32_16x16x32_bf16(A2h, Bhi, z1, 0, 0, 0);
    z1 = __builtin_amdgcn_mfma_f32_16x16x32_bf16(A2l, Bhi, z1, 0, 0, 0);
    z1 = __builtin_amdgcn_mfma_f32_16x16x32_bf16(A2h, Blo, z1, 0, 0, 0);
    float hv[8];
#pragma unroll
    for (int i = 0; i < 4; ++i) {
      hv[i]     = sigmoid_fast(z0[i]);
      hv[4 + i] = sigmoid_fast(z1[i]);
    }
    packB(hv);                                 // B for NEXT step, in-lane
    float hp = 0.f;
#pragma unroll
    for (int i = 0; i < 8; ++i)
      hp = fmaf(w1a[i], s1[i], fmaf(w2a[i], hv[i], hp));
    return redq(hp);                           // + hc2 by caller
  };

  float P = 0.f, Hprev = 0.f, Bprev = 0.f;
  float4 xc;

  if (chunk == 0) {
    // ---- t = 0 prologue (exact reference init) ----
    float4 xv = xb[0];
#pragma unroll
    for (int i = 0; i < 8; ++i)
      s1[i] = __builtin_amdgcn_fmed3f(s1[i] + xv.y, -rc[i], rc[i]);
    float hh = 0.f;
#pragma unroll
    for (int i = 0; i < 8; ++i) hh = fmaf(w1a[i], s1[i], hh);
    const float Hh0  = redq(hh) + hcst;
    const float hpre = (xv.x - Hh0) / sumW2;   // uniform initial h2
    float hv[8];
#pragma unroll
    for (int i = 0; i < 8; ++i) {
      const int row = (i < 4) ? (4*q + i) : (16 + 4*q + (i - 4));
      float rs = 0.f;
      if (row < HID)
        for (int u2 = 0; u2 < HID; ++u2) rs += Wh[row*HID + u2];
      float z = cva[i] + wx0[i]*xv.x + wx1[i]*xv.z + wx2[i]*xv.w + rs*hpre;
      hv[i] = sigmoid_fast(z);
    }
    packB(hv);
    // ---- t = 1..15 : recurrence only ----
    xc = xb[1];
    for (int t = 1; t < SKIP; ++t) {
      float4 xn = xb[t + 1];
      (void)dostep(xc);
      xc = xn;
    }                                          // xc == xb[ob]
  } else {
    // ---- s1-only exact prescan over [0, ob-WARM) ----
    const int ps = ob - WARM;                  // 248/496/744, %8==0
    const float* xf = x + (size_t)b * S_LEN * 4;
    for (int t = 0; t < ps; t += 8) {
      float d[8];
#pragma unroll
      for (int u = 0; u < 8; ++u) d[u] = xf[(t + u)*4 + 1];
#pragma unroll
      for (int u = 0; u < 8; ++u) {
#pragma unroll
        for (int i = 0; i < 8; ++i)
          s1[i] = __builtin_amdgcn_fmed3f(s1[i] + d[u], -rc[i], rc[i]);
      }
    }
    // ---- h2 warm-up over [ps, ob): 32 full steps from h=0.5 ----
    float hv[8];
#pragma unroll
    for (int i = 0; i < 8; ++i) hv[i] = 0.5f;
    packB(hv);
    float plast = 0.f;
    xc = xb[ps];
    for (int t = ps; t < ob; ++t) {
      float4 xn = xb[t + 1];
      plast = dostep(xc);
      Bprev = xc.x;
      xc = xn;
    }
    Hprev = plast + hc2;                       // xc == xb[ob]
  }

  // ---- output steps t = ob..oe-1 ----
  for (int t = ob; t < oe; t += 4) {
    float hq[4];
#pragma unroll
    for (int u = 0; u < 4; ++u) {
      int tn = t + u + 1; if (tn > oe - 1) tn = oe - 1;
      float4 xn = xb[tn];
      float Ht = dostep(xc) + hc2;
      if (t + u > SKIP) P += (xc.x - Bprev) * (Ht + Hprev);
      Hprev = Ht; Bprev = xc.x;
      hq[u] = Ht;
      xc = xn;
    }
    if (l < 16) {                              // q==0 lane stores batch c
      *(float4*)(Hout + (size_t)b * HLEN + (t - SKIP)) =
          make_float4(hq[0], hq[1], hq[2], hq[3]);
    }
  }

  // ---- cross-chunk trapezoid-sum reduction ----
  if (l < 16) Pred[chunk][c] = P;
  __syncthreads();

  // ==== fused MLP epilogue: 16 groups of 16 lanes, one batch each ====
  const int li = tid & 15;
  const int g  = tid >> 4;                     // 0..15
  const int be = blockIdx.x * 16 + g;
  const float Ptot = Pred[0][g] + Pred[1][g] + Pred[2][g] + Pred[3][g];
  const float e0 = var[be*4+0], e1 = var[be*4+1], e2 = var[be*4+2], e3 = var[be*4+3];
  const float am0 = amps[be*2+0], am1 = amps[be*2+1];

  float Pp = Ptot * 0.5f * am0 * am1;
  Pp *= __builtin_amdgcn_exp2f(e0 * 3.321928095f);     // * 10^var0
  Pp = fmaxf(Pp, 1e-12f);
  const float Pcv = __builtin_amdgcn_logf(Pp) * 0.30102999566f;  // log10

  float* hs = &mlpbuf[g][0];
#pragma unroll
  for (int qq = 0; qq < 4; ++qq) {
    const int n = li + 16 * qq;
    const float* wr = Wm1 + n * 5;
    float h1v = bm1[n] + wr[0]*e0 + wr[1]*e1 + wr[2]*e2 + wr[3]*e3 + wr[4]*Pcv;
    hs[n] = fmaxf(h1v, 0.f);                   // wave-synchronous in group
  }
  const int m0 = li, m1 = li + 16;
  const float4* h1v4 = (const float4*)hs;
  const float4* w2a4 = (const float4*)(Wm2 + m0 * 64);
  const float4* w2b4 = (const float4*)(Wm2 + m1 * 64);
  float zz0 = bm2[m0], zz1 = bm2[m1];
#pragma unroll
  for (int qq = 0; qq < 16; ++qq) {
    float4 hh = h1v4[qq];
    float4 wa = w2a4[qq], wb = w2b4[qq];
    zz0 += wa.x*hh.x + wa.y*hh.y + wa.z*hh.z + wa.w*hh.w;
    zz1 += wb.x*hh.x + wb.y*hh.y + wb.z*hh.z + wb.w*hh.w;
  }
  float sp = Wm3[m0] * fmaxf(zz0, 0.f) + Wm3[m1] * fmaxf(zz1, 0.f);
  sp = red16(sp);
  if (li == 0) out2[be] = Pcv + sp + bm3[0];
}

extern "C" void kernel_launch(void* const* d_in, const int* in_sizes, int n_in,
                              void* d_out, int out_size, void* d_ws, size_t ws_size,
                              hipStream_t stream)
{
  const float* x    = (const float*)d_in[0];
  const float* var  = (const float*)d_in[1];
  const float* amps = (const float*)d_in[2];
  const float* s0   = (const float*)d_in[3];
  const float* W1   = (const float*)d_in[4];
  const float* b1   = (const float*)d_in[5];
  const float* Wx   = (const float*)d_in[6];
  const float* Wh   = (const float*)d_in[7];
  const float* W2   = (const float*)d_in[8];
  const float* b2   = (const float*)d_in[9];
  const float* Wm1  = (const float*)d_in[10];
  const float* bm1  = (const float*)d_in[11];
  const float* Wm2  = (const float*)d_in[12];
  const float* bm2  = (const float*)d_in[13];
  const float* Wm3  = (const float*)d_in[14];
  const float* bm3  = (const float*)d_in[15];
  // d_in[16] = n_init (compile-time 16)

  float* Hout = (float*)d_out;
  float* out2 = (float*)d_out + (size_t)B_TOT * HLEN;

  mminet_fused<<<B_TOT / 16, 256, 0, stream>>>(
      x, var, amps, s0, W1, b1, Wx, Wh, W2, b2,
      Wm1, bm1, Wm2, bm2, Wm3, bm3, Hout, out2);
}